// Round 2
// baseline (2054.887 us; speedup 1.0000x reference)
//
#include <hip/hip_runtime.h>
#include <hip/hip_bf16.h>
#include <cstdint>
#include <cstddef>

// Problem constants
#define NXD 512
#define NQD 512
#define NUD 128
#define NBATCH 32768
#define EPSV 1e-3f
#define KBASE 640   // [xi | u]
#define KFIN 1152   // [xi | u | w]

typedef unsigned short u16;
typedef short bf16x8 __attribute__((ext_vector_type(8)));
typedef _Float16 f16x8 __attribute__((ext_vector_type(8)));
typedef float f32x4 __attribute__((ext_vector_type(4)));

__device__ __forceinline__ void gload_lds16(const u16* g, u16* l) {
  __builtin_amdgcn_global_load_lds((const __attribute__((address_space(1))) void*)g,
                                   (__attribute__((address_space(3))) void*)l, 16, 0, 0);
}

__device__ __forceinline__ float fast_tanh(float x) {
  float e = __expf(2.0f * x);
  return 1.0f - 2.0f / (e + 1.0f);
}

// ---------------------------------------------------------------------------
// gbar: software grid barrier. Monotone counter; target = (#barriers)*gridDim.
// RELEASE add publishes this block's writes; ACQUIRE spin + __syncthreads
// makes all blocks' writes visible to every thread. Agent scope => cross-XCD.
// Requires all blocks co-resident: grid=256 blocks on 256 CUs, small footprint.
// Counter zeroed by hipMemsetAsync before each launch (graph-replay safe).
// ---------------------------------------------------------------------------
__device__ __forceinline__ void gbar(unsigned int* bar, unsigned int target) {
  __syncthreads();
  if (threadIdx.x == 0) {
    __hip_atomic_fetch_add(bar, 1u, __ATOMIC_RELEASE, __HIP_MEMORY_SCOPE_AGENT);
    while (__hip_atomic_load(bar, __ATOMIC_ACQUIRE, __HIP_MEMORY_SCOPE_AGENT) < target)
      __builtin_amdgcn_s_sleep(2);
  }
  __syncthreads();
}

// ---------------------------------------------------------------------------
// tile_mm<TA,TB>: 64x64 output tile accumulation, 256 threads, 16-wide K steps.
//   TA=0: Aop(i,k) = A[(ai0+i)*lda + ak0+k]   TA=1: Aop(i,k) = A[(ak0+k)*lda + ai0+i]
//   TB=0: Bop(k,j) = B[(bk0+k)*ldb + bj0+j]   TB=1: Bop(k,j) = B[(bj0+j)*ldb + bk0+k]
// acc[i][j] += sum_k Aop(ty*4+i, k) * Bop(k, tx*4+j). K % 16 == 0.
// (verbatim machinery from the verified k_gemm_acc)
// ---------------------------------------------------------------------------
template <int TA, int TB>
__device__ __forceinline__ void tile_mm(float acc[4][4], float* As, float* Bs,
                                        const float* A, int lda, int ai0, int ak0,
                                        const float* B, int ldb, int bj0, int bk0,
                                        int K) {
  int tid = threadIdx.x;
  int tx = tid & 15, ty = tid >> 4;
  for (int kc = 0; kc < K; kc += 16) {
    float4 av, bv;
    if (TA == 0) {
      int row = tid >> 2, q4 = (tid & 3) * 4;
      av = *(const float4*)&A[(size_t)(ai0 + row) * lda + ak0 + kc + q4];
    } else {
      int kr = tid >> 4, m4 = (tid & 15) * 4;
      av = *(const float4*)&A[(size_t)(ak0 + kc + kr) * lda + ai0 + m4];
    }
    if (TB == 0) {
      int kr = tid >> 4, j4 = (tid & 15) * 4;
      bv = *(const float4*)&B[(size_t)(bk0 + kc + kr) * ldb + bj0 + j4];
    } else {
      int row = tid >> 2, q4 = (tid & 3) * 4;
      bv = *(const float4*)&B[(size_t)(bj0 + row) * ldb + bk0 + kc + q4];
    }
    __syncthreads();
    if (TA == 0) {
      int row = tid >> 2, q4 = (tid & 3) * 4;
      As[(q4 + 0) * 68 + row] = av.x; As[(q4 + 1) * 68 + row] = av.y;
      As[(q4 + 2) * 68 + row] = av.z; As[(q4 + 3) * 68 + row] = av.w;
    } else {
      int kr = tid >> 4, m4 = (tid & 15) * 4;
      *(float4*)&As[kr * 68 + m4] = av;
    }
    if (TB == 0) {
      int kr = tid >> 4, j4 = (tid & 15) * 4;
      *(float4*)&Bs[kr * 68 + j4] = bv;
    } else {
      int row = tid >> 2, q4 = (tid & 3) * 4;
      Bs[(q4 + 0) * 68 + row] = bv.x; Bs[(q4 + 1) * 68 + row] = bv.y;
      Bs[(q4 + 2) * 68 + row] = bv.z; Bs[(q4 + 3) * 68 + row] = bv.w;
    }
    __syncthreads();
#pragma unroll
    for (int kk = 0; kk < 16; ++kk) {
      float a4[4], b4[4];
      *(float4*)a4 = *(const float4*)&As[kk * 68 + ty * 4];
      *(float4*)b4 = *(const float4*)&Bs[kk * 68 + tx * 4];
#pragma unroll
      for (int i = 0; i < 4; ++i)
#pragma unroll
        for (int j = 0; j < 4; ++j) acc[i][j] += a4[i] * b4[j];
    }
  }
}

// ---------------------------------------------------------------------------
// chol_diag64: factor 64x64 diagonal block (verbatim from verified kernel),
// leaves L11 in Ls[4096] for the fused trsm. Block-internal only.
// ---------------------------------------------------------------------------
__device__ void chol_diag64(float* Pm, int kb, float* cb2, float* Ls) {
  int tid = threadIdx.x;
  int ty = tid >> 4, tx = tid & 15;
  int base = kb * 64;
  float T[4][4];
#pragma unroll
  for (int rr = 0; rr < 4; ++rr)
#pragma unroll
    for (int cc = 0; cc < 4; ++cc)
      T[rr][cc] = Pm[(size_t)(base + ty * 4 + rr) * 512 + base + tx * 4 + cc];

  for (int c = 0; c < 64; ++c) {
    float* cb = cb2 + (c & 1) * 72;
    if (tx == (c >> 2)) {
      int cc = c & 3;
#pragma unroll
      for (int rr = 0; rr < 4; ++rr) cb[ty * 4 + rr] = T[rr][cc];
    }
    __syncthreads();
    float dcv = cb[c];
    float dc = sqrtf(dcv);
    float rdc = 1.0f / dc;
    float rdcv = 1.0f / dcv;
    if (tx == (c >> 2)) {
      int cc = c & 3;
#pragma unroll
      for (int rr = 0; rr < 4; ++rr) {
        int r = ty * 4 + rr;
        if (r == c) T[rr][cc] = dc;
        else if (r > c) T[rr][cc] *= rdc;
      }
    }
    float cr[4], cj[4];
#pragma unroll
    for (int rr = 0; rr < 4; ++rr) {
      int r = ty * 4 + rr;
      cr[rr] = (r > c) ? cb[r] * rdcv : 0.0f;
    }
#pragma unroll
    for (int cc = 0; cc < 4; ++cc) {
      int j = tx * 4 + cc;
      cj[cc] = (j > c) ? cb[j] : 0.0f;
    }
#pragma unroll
    for (int rr = 0; rr < 4; ++rr)
#pragma unroll
      for (int cc = 0; cc < 4; ++cc) T[rr][cc] -= cr[rr] * cj[cc];
  }
  __syncthreads();
#pragma unroll
  for (int rr = 0; rr < 4; ++rr)
#pragma unroll
    for (int cc = 0; cc < 4; ++cc) {
      float v = T[rr][cc];
      Pm[(size_t)(base + ty * 4 + rr) * 512 + base + tx * 4 + cc] = v;
      Ls[(ty * 4 + rr) * 64 + tx * 4 + cc] = v;
    }
  __syncthreads();
}

// ---------------------------------------------------------------------------
// diag_inv64: X = inv(L[kb][kb]) (lower tri), written to Tinv diag block
// (upper-in-block zeros included). One block; thread j owns column j.
// ---------------------------------------------------------------------------
__device__ void diag_inv64(const float* Pm, float* Tinv, int kb, float* Ls, float* Xs) {
  int tid = threadIdx.x;
  int base = kb * 64;
  for (int idx = tid; idx < 4096; idx += 256) {
    Ls[idx] = Pm[(size_t)(base + (idx >> 6)) * 512 + base + (idx & 63)];
    Xs[idx] = 0.0f;
  }
  __syncthreads();
  if (tid < 64) {
    int j = tid;
    Xs[j * 64 + j] = 1.0f / Ls[j * 64 + j];
    for (int i = j + 1; i < 64; ++i) {
      float s = 0.0f;
      for (int k = j; k < i; ++k) s += Ls[i * 64 + k] * Xs[k * 64 + j];
      Xs[i * 64 + j] = -s / Ls[i * 64 + i];
    }
  }
  __syncthreads();
  for (int idx = tid; idx < 4096; idx += 256)
    Tinv[(size_t)(base + (idx >> 6)) * 512 + base + (idx & 63)] = Xs[idx];
  __syncthreads();
}

// ---------------------------------------------------------------------------
// k_small: the ENTIRE small-matrix stage as one kernel (plain launch).
// 256 blocks x 256 threads (grid == CU count -> co-residency by capacity).
// Phases (gbar between):
//  1  H = X@X^T + eps*I (256 tiles)  |  P = 0.5*Pstar@Pstar^T + eps*I (lower 36)
//  2  prep: lam, D11, C1, RHS(->Wm)
//  3  chol P, 8 panels: [b0: diag+trsm fused | b1: diag-inv of prev panel |
//       (kb==0) others zero Tinv] ; then lower trailing update (<=28 tiles)
//  4  Tinv = L^-1 by recursive doubling: 3 levels x {T=C@Ainv ; Inv21=-Binv@T}
//  5  Wm = Tinv^T @ (Tinv @ Wm)   (= P^-1 @ [Y | -H2-Chi])
//  6  pack Wbase/Wfin/D11h
// Scratch aliased into H (dead after phase 2): Z1=H, Tinv=H+512K, Tbuf=H+768K.
// ---------------------------------------------------------------------------
__global__ __launch_bounds__(256) void k_small(
    const float* __restrict__ X, const float* __restrict__ Pstar,
    const float* __restrict__ Y1, const float* __restrict__ Chi,
    const float* __restrict__ B2, const float* __restrict__ D12,
    float* __restrict__ H, float* __restrict__ Pm,
    float* __restrict__ D11, float* __restrict__ C1, float* __restrict__ Wm,
    __hip_bfloat16* __restrict__ Wbase, __hip_bfloat16* __restrict__ Wfin,
    u16* __restrict__ D11h, unsigned int* bar) {
  __shared__ float smem[8192];
  float* As = smem;
  float* Bs = smem + 1088;
  int bid = blockIdx.x;
  int tid = threadIdx.x;
  unsigned int bcnt = 0;

  float* Z1 = H;                 // 512 x 1024 (rows 0..511 of H)
  float* Tinv = H + 524288;      // 512 x 512  (rows 512..767 of H)
  float* Tbuf = H + 786432;      // up to 256x256 scratch (rows 768..1023)

  // ---- phase 1: syrks ----
  {
    int bi = bid >> 4, bj = bid & 15;
    float acc[4][4] = {};
    tile_mm<0, 1>(acc, As, Bs, X, 1024, bi * 64, 0, X, 1024, bj * 64, 0, 1024);
    int tx = tid & 15, ty = tid >> 4;
#pragma unroll
    for (int i = 0; i < 4; ++i)
#pragma unroll
      for (int j = 0; j < 4; ++j) {
        int r = bi * 64 + ty * 4 + i, c2 = bj * 64 + tx * 4 + j;
        float v = acc[i][j];
        if (r == c2) v += EPSV;
        H[(size_t)r * 1024 + c2] = v;
      }
  }
  if (bid < 36) {  // lower tiles of P only (upper never read)
    int pi = 0, r2 = bid;
    while (r2 > pi) { r2 -= pi + 1; ++pi; }
    int pj = r2;
    float acc[4][4] = {};
    tile_mm<0, 1>(acc, As, Bs, Pstar, 512, pi * 64, 0, Pstar, 512, pj * 64, 0, 512);
    int tx = tid & 15, ty = tid >> 4;
#pragma unroll
    for (int i = 0; i < 4; ++i)
#pragma unroll
      for (int j = 0; j < 4; ++j) {
        int r = pi * 64 + ty * 4 + i, c2 = pj * 64 + tx * 4 + j;
        float v = 0.5f * acc[i][j];
        if (r == c2) v += EPSV;
        Pm[(size_t)r * 512 + c2] = v;
      }
  }
  gbar(bar, (++bcnt) * 256u);

  // ---- phase 2: prep (rows 2*bid, 2*bid+1) ----
#pragma unroll
  for (int rr = 0; rr < 2; ++rr) {
    int i = bid * 2 + rr;
    float lam = 0.5f * H[(size_t)(512 + i) * 1024 + 512 + i];
    float rlam = 1.0f / lam;
    for (int j = tid; j < 512; j += 256) {
      float h4 = H[(size_t)(512 + i) * 1024 + 512 + j];
      D11[i * 512 + j] = (j < i) ? (-h4 * rlam) : 0.0f;
      C1[i * 512 + j] = Chi[(size_t)j * 512 + i] * rlam;
      float y = -0.5f * (H[(size_t)i * 1024 + j] + Y1[(size_t)i * 512 + j] - Y1[(size_t)j * 512 + i]);
      Wm[(size_t)i * 1024 + j] = y;
      Wm[(size_t)i * 1024 + 512 + j] = -H[(size_t)i * 1024 + 512 + j] - Chi[(size_t)i * 512 + j];
    }
  }
  gbar(bar, (++bcnt) * 256u);

  // ---- phase 3: Cholesky, 8 panels ----
  for (int kb = 0; kb < 8; ++kb) {
    // 3a: block 0 = diag factor + fused trsm; block 1 = diag-inv of panel kb-1;
    //     (kb==0) blocks>=2 zero Tinv.
    if (bid == 0) {
      chol_diag64(Pm, kb, smem + 4096, smem);
      int rem = 512 - (kb + 1) * 64;
      float* Ls = smem;
      for (int ch = 0; ch < rem; ch += 256) {
        int ir = ch + tid;
        if (ir < rem) {
          int i = (kb + 1) * 64 + ir;
          float x[64];
          float* Arow = &Pm[(size_t)i * 512 + kb * 64];
#pragma unroll
          for (int c = 0; c < 64; ++c) {
            float a0 = Arow[c], a1 = 0.f, a2 = 0.f, a3 = 0.f;
#pragma unroll
            for (int m = 0; m < c; m += 4) {
              a0 -= x[m] * Ls[c * 64 + m];
              if (m + 1 < c) a1 -= x[m + 1] * Ls[c * 64 + m + 1];
              if (m + 2 < c) a2 -= x[m + 2] * Ls[c * 64 + m + 2];
              if (m + 3 < c) a3 -= x[m + 3] * Ls[c * 64 + m + 3];
            }
            x[c] = ((a0 + a1) + (a2 + a3)) / Ls[c * 64 + c];
          }
#pragma unroll
          for (int c = 0; c < 64; ++c) Arow[c] = x[c];
        }
      }
    } else if (bid == 1 && kb > 0) {
      diag_inv64(Pm, Tinv, kb - 1, smem, smem + 4096);
    } else if (kb == 0 && bid >= 2) {
      for (int idx = (bid - 2) * 256 + tid; idx < 262144; idx += 254 * 256)
        Tinv[idx] = 0.0f;
    }
    gbar(bar, (++bcnt) * 256u);

    // 3b: lower trailing update tiles; at kb==7 (no tiles) do last diag-inv.
    int nr2 = 7 - kb;
    int count = nr2 * (nr2 + 1) / 2;
    if (bid < count) {
      int i = 0, r2 = bid;
      while (r2 > i) { r2 -= i + 1; ++i; }
      int j = r2;
      int p1 = (kb + 1) * 64;
      float acc[4][4] = {};
      tile_mm<0, 1>(acc, As, Bs, Pm, 512, p1 + i * 64, kb * 64,
                    Pm, 512, p1 + j * 64, kb * 64, 64);
      int tx = tid & 15, ty = tid >> 4;
#pragma unroll
      for (int ii = 0; ii < 4; ++ii)
#pragma unroll
        for (int jj = 0; jj < 4; ++jj)
          Pm[(size_t)(p1 + i * 64 + ty * 4 + ii) * 512 + p1 + j * 64 + tx * 4 + jj] -= acc[ii][jj];
    } else if (kb == 7 && bid == 0) {
      diag_inv64(Pm, Tinv, 7, smem, smem + 4096);
    }
    gbar(bar, (++bcnt) * 256u);
  }

  // ---- phase 4: Tinv = L^-1 by recursive doubling ----
  for (int l = 0; l < 3; ++l) {
    int s = 64 << l, sd = s >> 6, tpp = sd * sd;
    int ntil = (4 >> l) * tpp;
    int p = 0, ti = 0, tj = 0;
    if (bid < ntil) {
      p = bid / tpp;
      int t = bid % tpp;
      ti = t / sd;
      tj = t % sd;
    }
    int C0 = 2 * p * s, R0 = C0 + s;
    float* Tb = Tbuf + p * s * s;
    if (bid < ntil) {  // T = C @ Ainv
      float acc[4][4] = {};
      tile_mm<0, 0>(acc, As, Bs, Pm, 512, R0 + ti * 64, C0,
                    Tinv, 512, C0 + tj * 64, C0, s);
      int tx = tid & 15, ty = tid >> 4;
#pragma unroll
      for (int i = 0; i < 4; ++i)
#pragma unroll
        for (int j = 0; j < 4; ++j)
          Tb[(size_t)(ti * 64 + ty * 4 + i) * s + tj * 64 + tx * 4 + j] = acc[i][j];
    }
    gbar(bar, (++bcnt) * 256u);
    if (bid < ntil) {  // Inv21 = -Binv @ T
      float acc[4][4] = {};
      tile_mm<0, 0>(acc, As, Bs, Tinv, 512, R0 + ti * 64, R0,
                    Tb, s, tj * 64, 0, s);
      int tx = tid & 15, ty = tid >> 4;
#pragma unroll
      for (int i = 0; i < 4; ++i)
#pragma unroll
        for (int j = 0; j < 4; ++j)
          Tinv[(size_t)(R0 + ti * 64 + ty * 4 + i) * 512 + C0 + tj * 64 + tx * 4 + j] = -acc[i][j];
    }
    gbar(bar, (++bcnt) * 256u);
  }

  // ---- phase 5: Wm = Tinv^T @ (Tinv @ Wm) ----
  {
    int ti = bid >> 4, tj = bid & 15;
    if (bid < 128) {
      float acc[4][4] = {};
      tile_mm<0, 0>(acc, As, Bs, Tinv, 512, ti * 64, 0, Wm, 1024, tj * 64, 0, 512);
      int tx = tid & 15, ty = tid >> 4;
#pragma unroll
      for (int i = 0; i < 4; ++i)
#pragma unroll
        for (int j = 0; j < 4; ++j)
          Z1[(size_t)(ti * 64 + ty * 4 + i) * 1024 + tj * 64 + tx * 4 + j] = acc[i][j];
    }
    gbar(bar, (++bcnt) * 256u);
    if (bid < 128) {
      float acc[4][4] = {};
      tile_mm<1, 0>(acc, As, Bs, Tinv, 512, ti * 64, 0, Z1, 1024, tj * 64, 0, 512);
      int tx = tid & 15, ty = tid >> 4;
#pragma unroll
      for (int i = 0; i < 4; ++i)
#pragma unroll
        for (int j = 0; j < 4; ++j)
          Wm[(size_t)(ti * 64 + ty * 4 + i) * 1024 + tj * 64 + tx * 4 + j] = acc[i][j];
    }
    gbar(bar, (++bcnt) * 256u);
  }

  // ---- phase 6: pack Wbase / Wfin / D11h (rows 2*bid, 2*bid+1) ----
#pragma unroll
  for (int rr = 0; rr < 2; ++rr) {
    int n = bid * 2 + rr;
    for (int c = tid; c < KBASE; c += 256) {
      float v = (c < 512) ? C1[(size_t)n * 512 + c] : D12[(size_t)n * 128 + (c - 512)];
      Wbase[(size_t)n * KBASE + c] = __float2bfloat16(v);
    }
    for (int c = tid; c < KFIN; c += 256) {
      float v;
      if (c < 512) v = Wm[(size_t)n * 1024 + c];                 // A
      else if (c < 640) v = B2[(size_t)n * 128 + (c - 512)];     // B2
      else v = Wm[(size_t)n * 1024 + 512 + (c - 640)];           // B1
      Wfin[(size_t)n * KFIN + c] = __float2bfloat16(v);
    }
    for (int c = tid; c < 512; c += 256) {
      _Float16 h = (_Float16)D11[(size_t)n * 512 + c];
      D11h[(size_t)n * 512 + c] = *(u16*)&h;
    }
  }
}

// ---------------------------------------------------------------------------
// k_pack_z: Zb[b][0:512) = bf16(xi[b]), Zb[b][512:640) = bf16(u[b])
// ---------------------------------------------------------------------------
__global__ __launch_bounds__(256) void k_pack_z(const float* __restrict__ xi,
                                                const float* __restrict__ u,
                                                __hip_bfloat16* __restrict__ Zb) {
  size_t b = blockIdx.x;
  for (int c = threadIdx.x; c < KBASE; c += 256) {
    float v = (c < 512) ? xi[b * 512 + c] : u[b * 128 + (c - 512)];
    Zb[b * KFIN + c] = __float2bfloat16(v);
  }
}

// ---------------------------------------------------------------------------
// k_gemm_bf16: C[m][n] = sum_k Z[m][k] * W[n][k]   (both K-contiguous rows)
// 128x128 tile, BK=32, 256 threads = 4 waves in 2x2, 16x16x32 bf16 MFMA.
// ---------------------------------------------------------------------------
__global__ __launch_bounds__(256) void k_gemm_bf16(
    const u16* __restrict__ Z, int ldz,
    const u16* __restrict__ W, int ldw,
    float* __restrict__ C, int N, int K) {
  __shared__ u16 As[128 * 32];
  __shared__ u16 Bs[128 * 32];
  int tid = threadIdx.x;
  int l = tid & 63, wv = tid >> 6;
  size_t m0 = (size_t)blockIdx.x * 128;
  int n0 = blockIdx.y * 128;

  int ra = wv * 16 + (l >> 2);
  int gq = (l & 3) ^ ((l >> 2) & 3) ^ (l >> 4);
  const u16* ga0 = Z + (m0 + ra) * (size_t)ldz + gq * 8;
  const u16* ga1 = Z + (m0 + ra + 64) * (size_t)ldz + gq * 8;
  const u16* gb0 = W + (size_t)(n0 + ra) * ldw + gq * 8;
  const u16* gb1 = W + (size_t)(n0 + ra + 64) * ldw + gq * 8;
  u16* la0 = &As[wv * 512];
  u16* la1 = &As[2048 + wv * 512];
  u16* lb0 = &Bs[wv * 512];
  u16* lb1 = &Bs[2048 + wv * 512];

  int wm = (wv & 1) * 64, wn = (wv >> 1) * 64;
  int fr = l & 15;
  int fs = (l >> 4) ^ (l & 3) ^ ((l >> 2) & 3);
  int offa[4], offb[4];
#pragma unroll
  for (int t = 0; t < 4; ++t) {
    offa[t] = (wm + t * 16 + fr) * 32 + fs * 8;
    offb[t] = (wn + t * 16 + fr) * 32 + fs * 8;
  }

  f32x4 acc[4][4] = {};
  for (int k0 = 0; k0 < K; k0 += 32) {
    __syncthreads();
    gload_lds16(ga0, la0);
    gload_lds16(ga1, la1);
    gload_lds16(gb0, lb0);
    gload_lds16(gb1, lb1);
    ga0 += 32; ga1 += 32; gb0 += 32; gb1 += 32;
    __syncthreads();
    bf16x8 af[4], bfr[4];
#pragma unroll
    for (int t = 0; t < 4; ++t) {
      af[t] = *(const bf16x8*)&As[offa[t]];
      bfr[t] = *(const bf16x8*)&Bs[offb[t]];
    }
#pragma unroll
    for (int mt = 0; mt < 4; ++mt)
#pragma unroll
      for (int nt = 0; nt < 4; ++nt)
        acc[mt][nt] = __builtin_amdgcn_mfma_f32_16x16x32_bf16(af[mt], bfr[nt], acc[mt][nt], 0, 0, 0);
  }

#pragma unroll
  for (int mt = 0; mt < 4; ++mt)
#pragma unroll
    for (int nt = 0; nt < 4; ++nt) {
      int ncol = n0 + wn + nt * 16 + (l & 15);
#pragma unroll
      for (int r = 0; r < 4; ++r) {
        size_t mrow = m0 + wm + mt * 16 + (l >> 4) * 4 + r;
        C[mrow * N + ncol] = acc[mt][nt][r];
      }
    }
}

// ---------------------------------------------------------------------------
// k_scan_mfma: chunked recurrence, 32 chunks of 16 (unchanged).
// ---------------------------------------------------------------------------
#define WSTR 520  // u16 row stride (1040 B, 16B-aligned)
__global__ __launch_bounds__(256) void k_scan_mfma(
    const float* __restrict__ basep,    // 32768 x 512 fp32
    const float* __restrict__ D11,      // 512 x 512 fp32
    const u16* __restrict__ D11h,       // 512 x 512 fp16
    u16* __restrict__ zw) {             // Zb + 640, row stride KFIN (bf16)
  __shared__ u16 wbf_s[4][16 * WSTR];
  __shared__ float ptr_s[4][16 * 16];
  __shared__ float dls_s[4][16 * 16];

  int tid = threadIdx.x;
  int wv = tid >> 6, l = tid & 63;
  int r = l & 15;
  int q = l >> 4;
  size_t gm0 = (size_t)blockIdx.x * 64 + wv * 16;

  u16* wbf = wbf_s[wv];
  float* ptr = ptr_s[wv];
  float* dls = dls_s[wv];

  float wreg[4] = {0.f, 0.f, 0.f, 0.f};

  for (int c = 0; c < 32; ++c) {
    int i0 = c * 16;
    int nk = i0 >> 5;
    int rem = c & 1;
    const u16* drow = &D11h[(size_t)(i0 + r) * 512 + q * 8];
    f16x8 bfr[16];
#pragma unroll
    for (int k = 0; k < 16; ++k)
      if (k < nk) bfr[k] = *(const f16x8*)&drow[k * 32];
    f16x8 brem = {};
    if (rem && q < 2) brem = *(const f16x8*)&drow[nk * 32];
#pragma unroll
    for (int k = 0; k < 4; ++k) {
      int ii = q + 4 * k;
      dls[ii * 16 + r] = D11[(size_t)(i0 + ii) * 512 + i0 + r];
    }
    f32x4 acc = {0.f, 0.f, 0.f, 0.f};
#pragma unroll
    for (int k = 0; k < 16; ++k)
      if (k < nk) {
        f16x8 a = *(const f16x8*)&wbf[r * WSTR + k * 32 + q * 8];
        acc = __builtin_amdgcn_mfma_f32_16x16x32_f16(a, bfr[k], acc, 0, 0, 0);
      }
    if (rem) {
      f16x8 a = {};
      if (q < 2) a = *(const f16x8*)&wbf[r * WSTR + nk * 32 + q * 8];
      acc = __builtin_amdgcn_mfma_f32_16x16x32_f16(a, brem, acc, 0, 0, 0);
    }
#pragma unroll
    for (int reg = 0; reg < 4; ++reg)
      acc[reg] += basep[(gm0 + q * 4 + reg) * 512 + i0 + r];
#pragma unroll
    for (int reg = 0; reg < 4; ++reg) {
      int m = q * 4 + reg;
      int nsw = r ^ ((m & 3) << 2);
      ptr[m * 16 + nsw] = acc[reg];
    }
    float p[16];
#pragma unroll
    for (int j = 0; j < 4; ++j) {
      float4 v4 = *(const float4*)&ptr[r * 16 + j * 4];
      int cj = (j ^ (r & 3)) * 4;
      p[cj + 0] = v4.x; p[cj + 1] = v4.y; p[cj + 2] = v4.z; p[cj + 3] = v4.w;
    }
#pragma unroll
    for (int s = 0; s < 16; ++s) {
      float prod = 0.f;
#pragma unroll
      for (int m = 0; m < 4; ++m)
        prod = fmaf(wreg[m], dls[s * 16 + q + 4 * m], prod);
      prod += __shfl_xor(prod, 16);
      prod += __shfl_xor(prod, 32);
      float w = fast_tanh(p[s] + prod);
      if ((s & 3) == q) {
        wreg[s >> 2] = w;
        *(_Float16*)&wbf[r * WSTR + i0 + s] = (_Float16)w;
      }
    }
  }
#pragma unroll
  for (int it = 0; it < 16; ++it) {
    int idx = it * 64 + l;
    int row = idx >> 6;
    int ch = idx & 63;
    f16x8 v = *(const f16x8*)&wbf[row * WSTR + ch * 8];
    u16 o[8];
#pragma unroll
    for (int e = 0; e < 8; ++e) {
      __hip_bfloat16 b = __float2bfloat16((float)v[e]);
      o[e] = *(u16*)&b;
    }
    *(uint4*)&zw[(gm0 + row) * KFIN + ch * 8] = *(const uint4*)o;
  }
}

// ---------------------------------------------------------------------------
extern "C" void kernel_launch(void* const* d_in, const int* in_sizes, int n_in,
                              void* d_out, int out_size, void* d_ws, size_t ws_size,
                              hipStream_t stream) {
  const float* xi = (const float*)d_in[1];
  const float* u = (const float*)d_in[2];
  const float* Pstar = (const float*)d_in[3];
  const float* Chi = (const float*)d_in[4];
  const float* Y1 = (const float*)d_in[5];
  const float* B2 = (const float*)d_in[6];
  const float* D12 = (const float*)d_in[7];
  const float* X = (const float*)d_in[8];
  float* out = (float*)d_out;

  char* ws = (char*)d_ws;
  __hip_bfloat16* Zb = (__hip_bfloat16*)ws;                       // 32768 x 1152 bf16
  size_t off = (size_t)NBATCH * KFIN * sizeof(__hip_bfloat16);
  float* H = (float*)(ws + off);    off += (size_t)1024 * 1024 * 4;
  float* Pm = (float*)(ws + off);   off += (size_t)512 * 512 * 4;
  float* D11 = (float*)(ws + off);  off += (size_t)512 * 512 * 4;
  float* C1 = (float*)(ws + off);   off += (size_t)512 * 512 * 4;
  float* Wm = (float*)(ws + off);   off += (size_t)512 * 1024 * 4;
  __hip_bfloat16* Wbase = (__hip_bfloat16*)(ws + off); off += (size_t)512 * KBASE * 2;
  __hip_bfloat16* Wfin = (__hip_bfloat16*)(ws + off);  off += (size_t)512 * KFIN * 2;
  u16* D11h = (u16*)(ws + off);                        off += (size_t)512 * 512 * 2;
  unsigned int* bar = (unsigned int*)(ws + off);       off += 256;

  // ---- zero the barrier counter (graph node; re-zeroed on every replay) ----
  hipMemsetAsync(bar, 0, 256, stream);

  // ---- pack Z (xi|u) in bf16 ----
  k_pack_z<<<NBATCH, 256, 0, stream>>>(xi, u, Zb);

  // ---- entire small-matrix stage: ONE plain launch w/ software barrier ----
  k_small<<<256, 256, 0, stream>>>(X, Pstar, Y1, Chi, B2, D12, H, Pm,
                                   D11, C1, Wm, Wbase, Wfin, D11h, bar);

  // ---- big stage (bf16 MFMA) ----
  k_gemm_bf16<<<dim3(NBATCH / 128, NQD / 128), 256, 0, stream>>>(
      (const u16*)Zb, KFIN, (const u16*)Wbase, KBASE, out, NQD, KBASE);
  k_scan_mfma<<<NBATCH / 64, 256, 0, stream>>>(out, D11, D11h, (u16*)(Zb + KBASE));
  k_gemm_bf16<<<dim3(NBATCH / 128, NXD / 128), 256, 0, stream>>>(
      (const u16*)Zb, KFIN, (const u16*)Wfin, KFIN, out, NXD, KFIN);
}

// Round 4
// 1711.153 us; speedup vs baseline: 1.2009x; 1.2009x over previous
//
#include <hip/hip_runtime.h>
#include <hip/hip_bf16.h>
#include <cstdint>
#include <cstddef>

// Problem constants
#define NXD 512
#define NQD 512
#define NUD 128
#define NBATCH 32768
#define EPSV 1e-3f
#define KBASE 640   // [xi | u]
#define KFIN 1152   // [xi | u | w]

typedef unsigned short u16;
typedef short bf16x8 __attribute__((ext_vector_type(8)));
typedef _Float16 f16x8 __attribute__((ext_vector_type(8)));
typedef float f32x4 __attribute__((ext_vector_type(4)));

__device__ __forceinline__ void gload_lds16(const u16* g, u16* l) {
  __builtin_amdgcn_global_load_lds((const __attribute__((address_space(1))) void*)g,
                                   (__attribute__((address_space(3))) void*)l, 16, 0, 0);
}

__device__ __forceinline__ float fast_tanh(float x) {
  float e = __expf(2.0f * x);
  return 1.0f - 2.0f / (e + 1.0f);
}

// ---------------------------------------------------------------------------
// gbar: contention-free fan-out grid barrier (round-2's hot-line spin cost
// ~52us/barrier came from 256 pollers on ONE cacheline saturating the
// coherence point; here every line is polled by exactly one agent).
//   arr[b*16]: block b's arrive flag (64B apart). rel[b*16]: release flag.
//   Block 0 wave 0 sweeps arrive flags (lane g polls lines g, g+64, ...),
//   then fans out epoch to per-block release lines. Epochs are monotone;
//   flags zeroed by hipMemsetAsync before launch (graph-replay safe).
// Fences: __threadfence() = device-scope SC fence (cross-XCD visibility);
// per-flag stores/loads use __hip_atomic_* (compiled fine in round 2).
// ---------------------------------------------------------------------------
__device__ __forceinline__ void gbar(unsigned int* flags, unsigned int ep) {
  unsigned int* arr = flags;
  unsigned int* rel = flags + 4096;
  int tid = threadIdx.x, bid = blockIdx.x;
  __syncthreads();
  if (bid == 0) {
    if (tid == 0)
      __hip_atomic_store(&arr[0], ep, __ATOMIC_RELEASE, __HIP_MEMORY_SCOPE_AGENT);
    if (tid < 64) {
#pragma unroll
      for (int g = tid; g < 256; g += 64)
        while (__hip_atomic_load(&arr[g * 16], __ATOMIC_RELAXED, __HIP_MEMORY_SCOPE_AGENT) < ep)
          __builtin_amdgcn_s_sleep(4);
    }
    __threadfence();
    __syncthreads();
    if (tid < 64) {
#pragma unroll
      for (int g = tid; g < 256; g += 64)
        __hip_atomic_store(&rel[g * 16], ep, __ATOMIC_RELEASE, __HIP_MEMORY_SCOPE_AGENT);
    }
  } else {
    if (tid == 0) {
      __hip_atomic_store(&arr[bid * 16], ep, __ATOMIC_RELEASE, __HIP_MEMORY_SCOPE_AGENT);
      while (__hip_atomic_load(&rel[bid * 16], __ATOMIC_RELAXED, __HIP_MEMORY_SCOPE_AGENT) < ep)
        __builtin_amdgcn_s_sleep(4);
      __threadfence();
    }
    __syncthreads();
  }
}

// ---------------------------------------------------------------------------
// tile_mm<TA,TB>: 64x64 output tile accumulation, 256 threads, 16-wide K steps.
//   TA=0: Aop(i,k) = A[(ai0+i)*lda + ak0+k]   TA=1: Aop(i,k) = A[(ak0+k)*lda + ai0+i]
//   TB=0: Bop(k,j) = B[(bk0+k)*ldb + bj0+j]   TB=1: Bop(k,j) = B[(bj0+j)*ldb + bk0+k]
// acc[i][j] += sum_k Aop(ty*4+i, k) * Bop(k, tx*4+j). K % 16 == 0.
// ---------------------------------------------------------------------------
template <int TA, int TB>
__device__ __forceinline__ void tile_mm(float acc[4][4], float* As, float* Bs,
                                        const float* A, int lda, int ai0, int ak0,
                                        const float* B, int ldb, int bj0, int bk0,
                                        int K) {
  int tid = threadIdx.x;
  int tx = tid & 15, ty = tid >> 4;
  for (int kc = 0; kc < K; kc += 16) {
    float4 av, bv;
    if (TA == 0) {
      int row = tid >> 2, q4 = (tid & 3) * 4;
      av = *(const float4*)&A[(size_t)(ai0 + row) * lda + ak0 + kc + q4];
    } else {
      int kr = tid >> 4, m4 = (tid & 15) * 4;
      av = *(const float4*)&A[(size_t)(ak0 + kc + kr) * lda + ai0 + m4];
    }
    if (TB == 0) {
      int kr = tid >> 4, j4 = (tid & 15) * 4;
      bv = *(const float4*)&B[(size_t)(bk0 + kc + kr) * ldb + bj0 + j4];
    } else {
      int row = tid >> 2, q4 = (tid & 3) * 4;
      bv = *(const float4*)&B[(size_t)(bj0 + row) * ldb + bk0 + kc + q4];
    }
    __syncthreads();
    if (TA == 0) {
      int row = tid >> 2, q4 = (tid & 3) * 4;
      As[(q4 + 0) * 68 + row] = av.x; As[(q4 + 1) * 68 + row] = av.y;
      As[(q4 + 2) * 68 + row] = av.z; As[(q4 + 3) * 68 + row] = av.w;
    } else {
      int kr = tid >> 4, m4 = (tid & 15) * 4;
      *(float4*)&As[kr * 68 + m4] = av;
    }
    if (TB == 0) {
      int kr = tid >> 4, j4 = (tid & 15) * 4;
      *(float4*)&Bs[kr * 68 + j4] = bv;
    } else {
      int row = tid >> 2, q4 = (tid & 3) * 4;
      Bs[(q4 + 0) * 68 + row] = bv.x; Bs[(q4 + 1) * 68 + row] = bv.y;
      Bs[(q4 + 2) * 68 + row] = bv.z; Bs[(q4 + 3) * 68 + row] = bv.w;
    }
    __syncthreads();
#pragma unroll
    for (int kk = 0; kk < 16; ++kk) {
      float a4[4], b4[4];
      *(float4*)a4 = *(const float4*)&As[kk * 68 + ty * 4];
      *(float4*)b4 = *(const float4*)&Bs[kk * 68 + tx * 4];
#pragma unroll
      for (int i = 0; i < 4; ++i)
#pragma unroll
        for (int j = 0; j < 4; ++j) acc[i][j] += a4[i] * b4[j];
    }
  }
}

// ---------------------------------------------------------------------------
// chol_diag64: factor 64x64 diagonal block; leaves L11 in Ls[4096].
// ---------------------------------------------------------------------------
__device__ void chol_diag64(float* Pm, int kb, float* cb2, float* Ls) {
  int tid = threadIdx.x;
  int ty = tid >> 4, tx = tid & 15;
  int base = kb * 64;
  float T[4][4];
#pragma unroll
  for (int rr = 0; rr < 4; ++rr)
#pragma unroll
    for (int cc = 0; cc < 4; ++cc)
      T[rr][cc] = Pm[(size_t)(base + ty * 4 + rr) * 512 + base + tx * 4 + cc];

  for (int c = 0; c < 64; ++c) {
    float* cb = cb2 + (c & 1) * 72;
    if (tx == (c >> 2)) {
      int cc = c & 3;
#pragma unroll
      for (int rr = 0; rr < 4; ++rr) cb[ty * 4 + rr] = T[rr][cc];
    }
    __syncthreads();
    float dcv = cb[c];
    float dc = sqrtf(dcv);
    float rdc = 1.0f / dc;
    float rdcv = 1.0f / dcv;
    if (tx == (c >> 2)) {
      int cc = c & 3;
#pragma unroll
      for (int rr = 0; rr < 4; ++rr) {
        int r = ty * 4 + rr;
        if (r == c) T[rr][cc] = dc;
        else if (r > c) T[rr][cc] *= rdc;
      }
    }
    float cr[4], cj[4];
#pragma unroll
    for (int rr = 0; rr < 4; ++rr) {
      int r = ty * 4 + rr;
      cr[rr] = (r > c) ? cb[r] * rdcv : 0.0f;
    }
#pragma unroll
    for (int cc = 0; cc < 4; ++cc) {
      int j = tx * 4 + cc;
      cj[cc] = (j > c) ? cb[j] : 0.0f;
    }
#pragma unroll
    for (int rr = 0; rr < 4; ++rr)
#pragma unroll
      for (int cc = 0; cc < 4; ++cc) T[rr][cc] -= cr[rr] * cj[cc];
  }
  __syncthreads();
#pragma unroll
  for (int rr = 0; rr < 4; ++rr)
#pragma unroll
    for (int cc = 0; cc < 4; ++cc) {
      float v = T[rr][cc];
      Pm[(size_t)(base + ty * 4 + rr) * 512 + base + tx * 4 + cc] = v;
      Ls[(ty * 4 + rr) * 64 + tx * 4 + cc] = v;
    }
  __syncthreads();
}

// ---------------------------------------------------------------------------
// diag_inv64: X = inv(L[kb][kb]) (lower tri), into Tinv diag block.
// ---------------------------------------------------------------------------
__device__ void diag_inv64(const float* Pm, float* Tinv, int kb, float* Ls, float* Xs) {
  int tid = threadIdx.x;
  int base = kb * 64;
  for (int idx = tid; idx < 4096; idx += 256) {
    Ls[idx] = Pm[(size_t)(base + (idx >> 6)) * 512 + base + (idx & 63)];
    Xs[idx] = 0.0f;
  }
  __syncthreads();
  if (tid < 64) {
    int j = tid;
    Xs[j * 64 + j] = 1.0f / Ls[j * 64 + j];
    for (int i = j + 1; i < 64; ++i) {
      float s = 0.0f;
      for (int k = j; k < i; ++k) s += Ls[i * 64 + k] * Xs[k * 64 + j];
      Xs[i * 64 + j] = -s / Ls[i * 64 + i];
    }
  }
  __syncthreads();
  for (int idx = tid; idx < 4096; idx += 256)
    Tinv[(size_t)(base + (idx >> 6)) * 512 + base + (idx & 63)] = Xs[idx];
  __syncthreads();
}

// ---------------------------------------------------------------------------
// k_small: the ENTIRE small-matrix stage as one kernel (plain launch).
// 256 blocks x 256 threads; phases separated by fan-out gbar.
// ---------------------------------------------------------------------------
__global__ __launch_bounds__(256) void k_small(
    const float* __restrict__ X, const float* __restrict__ Pstar,
    const float* __restrict__ Y1, const float* __restrict__ Chi,
    const float* __restrict__ B2, const float* __restrict__ D12,
    float* __restrict__ H, float* __restrict__ Pm,
    float* __restrict__ D11, float* __restrict__ C1, float* __restrict__ Wm,
    __hip_bfloat16* __restrict__ Wbase, __hip_bfloat16* __restrict__ Wfin,
    u16* __restrict__ D11h, unsigned int* bar) {
  __shared__ float smem[8192];
  float* As = smem;
  float* Bs = smem + 1088;
  int bid = blockIdx.x;
  int tid = threadIdx.x;
  unsigned int bcnt = 0;

  float* Z1 = H;                 // 512 x 1024 (rows 0..511 of H)
  float* Tinv = H + 524288;      // 512 x 512  (rows 512..767 of H)
  float* Tbuf = H + 786432;      // up to 256x256 scratch (rows 768..1023)

  // ---- phase 1: syrks ----
  {
    int bi = bid >> 4, bj = bid & 15;
    float acc[4][4] = {};
    tile_mm<0, 1>(acc, As, Bs, X, 1024, bi * 64, 0, X, 1024, bj * 64, 0, 1024);
    int tx = tid & 15, ty = tid >> 4;
#pragma unroll
    for (int i = 0; i < 4; ++i)
#pragma unroll
      for (int j = 0; j < 4; ++j) {
        int r = bi * 64 + ty * 4 + i, c2 = bj * 64 + tx * 4 + j;
        float v = acc[i][j];
        if (r == c2) v += EPSV;
        H[(size_t)r * 1024 + c2] = v;
      }
  }
  if (bid < 36) {  // lower tiles of P only (upper never read)
    int pi = 0, r2 = bid;
    while (r2 > pi) { r2 -= pi + 1; ++pi; }
    int pj = r2;
    float acc[4][4] = {};
    tile_mm<0, 1>(acc, As, Bs, Pstar, 512, pi * 64, 0, Pstar, 512, pj * 64, 0, 512);
    int tx = tid & 15, ty = tid >> 4;
#pragma unroll
    for (int i = 0; i < 4; ++i)
#pragma unroll
      for (int j = 0; j < 4; ++j) {
        int r = pi * 64 + ty * 4 + i, c2 = pj * 64 + tx * 4 + j;
        float v = 0.5f * acc[i][j];
        if (r == c2) v += EPSV;
        Pm[(size_t)r * 512 + c2] = v;
      }
  }
  gbar(bar, ++bcnt);

  // ---- phase 2: prep (rows 2*bid, 2*bid+1) ----
#pragma unroll
  for (int rr = 0; rr < 2; ++rr) {
    int i = bid * 2 + rr;
    float lam = 0.5f * H[(size_t)(512 + i) * 1024 + 512 + i];
    float rlam = 1.0f / lam;
    for (int j = tid; j < 512; j += 256) {
      float h4 = H[(size_t)(512 + i) * 1024 + 512 + j];
      D11[i * 512 + j] = (j < i) ? (-h4 * rlam) : 0.0f;
      C1[i * 512 + j] = Chi[(size_t)j * 512 + i] * rlam;
      float y = -0.5f * (H[(size_t)i * 1024 + j] + Y1[(size_t)i * 512 + j] - Y1[(size_t)j * 512 + i]);
      Wm[(size_t)i * 1024 + j] = y;
      Wm[(size_t)i * 1024 + 512 + j] = -H[(size_t)i * 1024 + 512 + j] - Chi[(size_t)i * 512 + j];
    }
  }
  gbar(bar, ++bcnt);

  // ---- phase 3: Cholesky, 8 panels ----
  for (int kb = 0; kb < 8; ++kb) {
    // 3a: block 0 = diag factor + fused trsm; block 1 = diag-inv of prev panel;
    //     (kb==0) others zero Tinv.
    if (bid == 0) {
      chol_diag64(Pm, kb, smem + 4096, smem);
      int rem = 512 - (kb + 1) * 64;
      float* Ls = smem;
      for (int ch = 0; ch < rem; ch += 256) {
        int ir = ch + tid;
        if (ir < rem) {
          int i = (kb + 1) * 64 + ir;
          float x[64];
          float* Arow = &Pm[(size_t)i * 512 + kb * 64];
#pragma unroll
          for (int c = 0; c < 64; ++c) {
            float a0 = Arow[c], a1 = 0.f, a2 = 0.f, a3 = 0.f;
#pragma unroll
            for (int m = 0; m < c; m += 4) {
              a0 -= x[m] * Ls[c * 64 + m];
              if (m + 1 < c) a1 -= x[m + 1] * Ls[c * 64 + m + 1];
              if (m + 2 < c) a2 -= x[m + 2] * Ls[c * 64 + m + 2];
              if (m + 3 < c) a3 -= x[m + 3] * Ls[c * 64 + m + 3];
            }
            x[c] = ((a0 + a1) + (a2 + a3)) / Ls[c * 64 + c];
          }
#pragma unroll
          for (int c = 0; c < 64; ++c) Arow[c] = x[c];
        }
      }
    } else if (bid == 1 && kb > 0) {
      diag_inv64(Pm, Tinv, kb - 1, smem, smem + 4096);
    } else if (kb == 0 && bid >= 2) {
      for (int idx = (bid - 2) * 256 + tid; idx < 262144; idx += 254 * 256)
        Tinv[idx] = 0.0f;
    }
    gbar(bar, ++bcnt);

    // 3b: lower trailing update tiles; at kb==7 (no tiles) do last diag-inv.
    int nr2 = 7 - kb;
    int count = nr2 * (nr2 + 1) / 2;
    if (bid < count) {
      int i = 0, r2 = bid;
      while (r2 > i) { r2 -= i + 1; ++i; }
      int j = r2;
      int p1 = (kb + 1) * 64;
      float acc[4][4] = {};
      tile_mm<0, 1>(acc, As, Bs, Pm, 512, p1 + i * 64, kb * 64,
                    Pm, 512, p1 + j * 64, kb * 64, 64);
      int tx = tid & 15, ty = tid >> 4;
#pragma unroll
      for (int ii = 0; ii < 4; ++ii)
#pragma unroll
        for (int jj = 0; jj < 4; ++jj)
          Pm[(size_t)(p1 + i * 64 + ty * 4 + ii) * 512 + p1 + j * 64 + tx * 4 + jj] -= acc[ii][jj];
    } else if (kb == 7 && bid == 0) {
      diag_inv64(Pm, Tinv, 7, smem, smem + 4096);
    }
    gbar(bar, ++bcnt);
  }

  // ---- phase 4: Tinv = L^-1 by recursive doubling ----
  for (int l = 0; l < 3; ++l) {
    int s = 64 << l, sd = s >> 6, tpp = sd * sd;
    int ntil = (4 >> l) * tpp;
    int p = 0, ti = 0, tj = 0;
    if (bid < ntil) {
      p = bid / tpp;
      int t = bid % tpp;
      ti = t / sd;
      tj = t % sd;
    }
    int C0 = 2 * p * s, R0 = C0 + s;
    float* Tb = Tbuf + p * s * s;
    if (bid < ntil) {  // T = C @ Ainv
      float acc[4][4] = {};
      tile_mm<0, 0>(acc, As, Bs, Pm, 512, R0 + ti * 64, C0,
                    Tinv, 512, C0 + tj * 64, C0, s);
      int tx = tid & 15, ty = tid >> 4;
#pragma unroll
      for (int i = 0; i < 4; ++i)
#pragma unroll
        for (int j = 0; j < 4; ++j)
          Tb[(size_t)(ti * 64 + ty * 4 + i) * s + tj * 64 + tx * 4 + j] = acc[i][j];
    }
    gbar(bar, ++bcnt);
    if (bid < ntil) {  // Inv21 = -Binv @ T
      float acc[4][4] = {};
      tile_mm<0, 0>(acc, As, Bs, Tinv, 512, R0 + ti * 64, R0,
                    Tb, s, tj * 64, 0, s);
      int tx = tid & 15, ty = tid >> 4;
#pragma unroll
      for (int i = 0; i < 4; ++i)
#pragma unroll
        for (int j = 0; j < 4; ++j)
          Tinv[(size_t)(R0 + ti * 64 + ty * 4 + i) * 512 + C0 + tj * 64 + tx * 4 + j] = -acc[i][j];
    }
    gbar(bar, ++bcnt);
  }

  // ---- phase 5: Wm = Tinv^T @ (Tinv @ Wm) ----
  {
    int ti = bid >> 4, tj = bid & 15;
    if (bid < 128) {
      float acc[4][4] = {};
      tile_mm<0, 0>(acc, As, Bs, Tinv, 512, ti * 64, 0, Wm, 1024, tj * 64, 0, 512);
      int tx = tid & 15, ty = tid >> 4;
#pragma unroll
      for (int i = 0; i < 4; ++i)
#pragma unroll
        for (int j = 0; j < 4; ++j)
          Z1[(size_t)(ti * 64 + ty * 4 + i) * 1024 + tj * 64 + tx * 4 + j] = acc[i][j];
    }
    gbar(bar, ++bcnt);
    if (bid < 128) {
      float acc[4][4] = {};
      tile_mm<1, 0>(acc, As, Bs, Tinv, 512, ti * 64, 0, Z1, 1024, tj * 64, 0, 512);
      int tx = tid & 15, ty = tid >> 4;
#pragma unroll
      for (int i = 0; i < 4; ++i)
#pragma unroll
        for (int j = 0; j < 4; ++j)
          Wm[(size_t)(ti * 64 + ty * 4 + i) * 1024 + tj * 64 + tx * 4 + j] = acc[i][j];
    }
    gbar(bar, ++bcnt);
  }

  // ---- phase 6: pack Wbase / Wfin / D11h (rows 2*bid, 2*bid+1) ----
#pragma unroll
  for (int rr = 0; rr < 2; ++rr) {
    int n = bid * 2 + rr;
    for (int c = tid; c < KBASE; c += 256) {
      float v = (c < 512) ? C1[(size_t)n * 512 + c] : D12[(size_t)n * 128 + (c - 512)];
      Wbase[(size_t)n * KBASE + c] = __float2bfloat16(v);
    }
    for (int c = tid; c < KFIN; c += 256) {
      float v;
      if (c < 512) v = Wm[(size_t)n * 1024 + c];                 // A
      else if (c < 640) v = B2[(size_t)n * 128 + (c - 512)];     // B2
      else v = Wm[(size_t)n * 1024 + 512 + (c - 640)];           // B1
      Wfin[(size_t)n * KFIN + c] = __float2bfloat16(v);
    }
    for (int c = tid; c < 512; c += 256) {
      _Float16 h = (_Float16)D11[(size_t)n * 512 + c];
      D11h[(size_t)n * 512 + c] = *(u16*)&h;
    }
  }
}

// ---------------------------------------------------------------------------
// k_pack_z: Zb[b][0:512) = bf16(xi[b]), Zb[b][512:640) = bf16(u[b])
// ---------------------------------------------------------------------------
__global__ __launch_bounds__(256) void k_pack_z(const float* __restrict__ xi,
                                                const float* __restrict__ u,
                                                __hip_bfloat16* __restrict__ Zb) {
  size_t b = blockIdx.x;
  for (int c = threadIdx.x; c < KBASE; c += 256) {
    float v = (c < 512) ? xi[b * 512 + c] : u[b * 128 + (c - 512)];
    Zb[b * KFIN + c] = __float2bfloat16(v);
  }
}

// ---------------------------------------------------------------------------
// k_gemm_bf16: C[m][n] = sum_k Z[m][k] * W[n][k]   (both K-contiguous rows)
// 128x128 tile, BK=32, 256 threads = 4 waves in 2x2, 16x16x32 bf16 MFMA.
// ---------------------------------------------------------------------------
__global__ __launch_bounds__(256) void k_gemm_bf16(
    const u16* __restrict__ Z, int ldz,
    const u16* __restrict__ W, int ldw,
    float* __restrict__ C, int N, int K) {
  __shared__ u16 As[128 * 32];
  __shared__ u16 Bs[128 * 32];
  int tid = threadIdx.x;
  int l = tid & 63, wv = tid >> 6;
  size_t m0 = (size_t)blockIdx.x * 128;
  int n0 = blockIdx.y * 128;

  int ra = wv * 16 + (l >> 2);
  int gq = (l & 3) ^ ((l >> 2) & 3) ^ (l >> 4);
  const u16* ga0 = Z + (m0 + ra) * (size_t)ldz + gq * 8;
  const u16* ga1 = Z + (m0 + ra + 64) * (size_t)ldz + gq * 8;
  const u16* gb0 = W + (size_t)(n0 + ra) * ldw + gq * 8;
  const u16* gb1 = W + (size_t)(n0 + ra + 64) * ldw + gq * 8;
  u16* la0 = &As[wv * 512];
  u16* la1 = &As[2048 + wv * 512];
  u16* lb0 = &Bs[wv * 512];
  u16* lb1 = &Bs[2048 + wv * 512];

  int wm = (wv & 1) * 64, wn = (wv >> 1) * 64;
  int fr = l & 15;
  int fs = (l >> 4) ^ (l & 3) ^ ((l >> 2) & 3);
  int offa[4], offb[4];
#pragma unroll
  for (int t = 0; t < 4; ++t) {
    offa[t] = (wm + t * 16 + fr) * 32 + fs * 8;
    offb[t] = (wn + t * 16 + fr) * 32 + fs * 8;
  }

  f32x4 acc[4][4] = {};
  for (int k0 = 0; k0 < K; k0 += 32) {
    __syncthreads();
    gload_lds16(ga0, la0);
    gload_lds16(ga1, la1);
    gload_lds16(gb0, lb0);
    gload_lds16(gb1, lb1);
    ga0 += 32; ga1 += 32; gb0 += 32; gb1 += 32;
    __syncthreads();
    bf16x8 af[4], bfr[4];
#pragma unroll
    for (int t = 0; t < 4; ++t) {
      af[t] = *(const bf16x8*)&As[offa[t]];
      bfr[t] = *(const bf16x8*)&Bs[offb[t]];
    }
#pragma unroll
    for (int mt = 0; mt < 4; ++mt)
#pragma unroll
      for (int nt = 0; nt < 4; ++nt)
        acc[mt][nt] = __builtin_amdgcn_mfma_f32_16x16x32_bf16(af[mt], bfr[nt], acc[mt][nt], 0, 0, 0);
  }

#pragma unroll
  for (int mt = 0; mt < 4; ++mt)
#pragma unroll
    for (int nt = 0; nt < 4; ++nt) {
      int ncol = n0 + wn + nt * 16 + (l & 15);
#pragma unroll
      for (int r = 0; r < 4; ++r) {
        size_t mrow = m0 + wm + mt * 16 + (l >> 4) * 4 + r;
        C[mrow * N + ncol] = acc[mt][nt][r];
      }
    }
}

// ---------------------------------------------------------------------------
// k_scan_mfma: chunked recurrence, 32 chunks of 16 (unchanged).
// ---------------------------------------------------------------------------
#define WSTR 520  // u16 row stride (1040 B, 16B-aligned)
__global__ __launch_bounds__(256) void k_scan_mfma(
    const float* __restrict__ basep,    // 32768 x 512 fp32
    const float* __restrict__ D11,      // 512 x 512 fp32
    const u16* __restrict__ D11h,       // 512 x 512 fp16
    u16* __restrict__ zw) {             // Zb + 640, row stride KFIN (bf16)
  __shared__ u16 wbf_s[4][16 * WSTR];
  __shared__ float ptr_s[4][16 * 16];
  __shared__ float dls_s[4][16 * 16];

  int tid = threadIdx.x;
  int wv = tid >> 6, l = tid & 63;
  int r = l & 15;
  int q = l >> 4;
  size_t gm0 = (size_t)blockIdx.x * 64 + wv * 16;

  u16* wbf = wbf_s[wv];
  float* ptr = ptr_s[wv];
  float* dls = dls_s[wv];

  float wreg[4] = {0.f, 0.f, 0.f, 0.f};

  for (int c = 0; c < 32; ++c) {
    int i0 = c * 16;
    int nk = i0 >> 5;
    int rem = c & 1;
    const u16* drow = &D11h[(size_t)(i0 + r) * 512 + q * 8];
    f16x8 bfr[16];
#pragma unroll
    for (int k = 0; k < 16; ++k)
      if (k < nk) bfr[k] = *(const f16x8*)&drow[k * 32];
    f16x8 brem = {};
    if (rem && q < 2) brem = *(const f16x8*)&drow[nk * 32];
#pragma unroll
    for (int k = 0; k < 4; ++k) {
      int ii = q + 4 * k;
      dls[ii * 16 + r] = D11[(size_t)(i0 + ii) * 512 + i0 + r];
    }
    f32x4 acc = {0.f, 0.f, 0.f, 0.f};
#pragma unroll
    for (int k = 0; k < 16; ++k)
      if (k < nk) {
        f16x8 a = *(const f16x8*)&wbf[r * WSTR + k * 32 + q * 8];
        acc = __builtin_amdgcn_mfma_f32_16x16x32_f16(a, bfr[k], acc, 0, 0, 0);
      }
    if (rem) {
      f16x8 a = {};
      if (q < 2) a = *(const f16x8*)&wbf[r * WSTR + nk * 32 + q * 8];
      acc = __builtin_amdgcn_mfma_f32_16x16x32_f16(a, brem, acc, 0, 0, 0);
    }
#pragma unroll
    for (int reg = 0; reg < 4; ++reg)
      acc[reg] += basep[(gm0 + q * 4 + reg) * 512 + i0 + r];
#pragma unroll
    for (int reg = 0; reg < 4; ++reg) {
      int m = q * 4 + reg;
      int nsw = r ^ ((m & 3) << 2);
      ptr[m * 16 + nsw] = acc[reg];
    }
    float p[16];
#pragma unroll
    for (int j = 0; j < 4; ++j) {
      float4 v4 = *(const float4*)&ptr[r * 16 + j * 4];
      int cj = (j ^ (r & 3)) * 4;
      p[cj + 0] = v4.x; p[cj + 1] = v4.y; p[cj + 2] = v4.z; p[cj + 3] = v4.w;
    }
#pragma unroll
    for (int s = 0; s < 16; ++s) {
      float prod = 0.f;
#pragma unroll
      for (int m = 0; m < 4; ++m)
        prod = fmaf(wreg[m], dls[s * 16 + q + 4 * m], prod);
      prod += __shfl_xor(prod, 16);
      prod += __shfl_xor(prod, 32);
      float w = fast_tanh(p[s] + prod);
      if ((s & 3) == q) {
        wreg[s >> 2] = w;
        *(_Float16*)&wbf[r * WSTR + i0 + s] = (_Float16)w;
      }
    }
  }
#pragma unroll
  for (int it = 0; it < 16; ++it) {
    int idx = it * 64 + l;
    int row = idx >> 6;
    int ch = idx & 63;
    f16x8 v = *(const f16x8*)&wbf[row * WSTR + ch * 8];
    u16 o[8];
#pragma unroll
    for (int e = 0; e < 8; ++e) {
      __hip_bfloat16 b = __float2bfloat16((float)v[e]);
      o[e] = *(u16*)&b;
    }
    *(uint4*)&zw[(gm0 + row) * KFIN + ch * 8] = *(const uint4*)o;
  }
}

// ---------------------------------------------------------------------------
extern "C" void kernel_launch(void* const* d_in, const int* in_sizes, int n_in,
                              void* d_out, int out_size, void* d_ws, size_t ws_size,
                              hipStream_t stream) {
  const float* xi = (const float*)d_in[1];
  const float* u = (const float*)d_in[2];
  const float* Pstar = (const float*)d_in[3];
  const float* Chi = (const float*)d_in[4];
  const float* Y1 = (const float*)d_in[5];
  const float* B2 = (const float*)d_in[6];
  const float* D12 = (const float*)d_in[7];
  const float* X = (const float*)d_in[8];
  float* out = (float*)d_out;

  char* ws = (char*)d_ws;
  __hip_bfloat16* Zb = (__hip_bfloat16*)ws;                       // 32768 x 1152 bf16
  size_t off = (size_t)NBATCH * KFIN * sizeof(__hip_bfloat16);
  float* H = (float*)(ws + off);    off += (size_t)1024 * 1024 * 4;
  float* Pm = (float*)(ws + off);   off += (size_t)512 * 512 * 4;
  float* D11 = (float*)(ws + off);  off += (size_t)512 * 512 * 4;
  float* C1 = (float*)(ws + off);   off += (size_t)512 * 512 * 4;
  float* Wm = (float*)(ws + off);   off += (size_t)512 * 1024 * 4;
  __hip_bfloat16* Wbase = (__hip_bfloat16*)(ws + off); off += (size_t)512 * KBASE * 2;
  __hip_bfloat16* Wfin = (__hip_bfloat16*)(ws + off);  off += (size_t)512 * KFIN * 2;
  u16* D11h = (u16*)(ws + off);                        off += (size_t)512 * 512 * 2;
  unsigned int* bar = (unsigned int*)(ws + off);       off += 32768;  // arr[4096] + rel[4096] uints

  // ---- zero the barrier flags (graph node; re-zeroed on every replay) ----
  (void)hipMemsetAsync(bar, 0, 32768, stream);

  // ---- pack Z (xi|u) in bf16 ----
  k_pack_z<<<NBATCH, 256, 0, stream>>>(xi, u, Zb);

  // ---- entire small-matrix stage: ONE plain launch w/ fan-out barrier ----
  k_small<<<256, 256, 0, stream>>>(X, Pstar, Y1, Chi, B2, D12, H, Pm,
                                   D11, C1, Wm, Wbase, Wfin, D11h, bar);

  // ---- big stage (bf16 MFMA) ----
  k_gemm_bf16<<<dim3(NBATCH / 128, NQD / 128), 256, 0, stream>>>(
      (const u16*)Zb, KFIN, (const u16*)Wbase, KBASE, out, NQD, KBASE);
  k_scan_mfma<<<NBATCH / 64, 256, 0, stream>>>(out, D11, D11h, (u16*)(Zb + KBASE));
  k_gemm_bf16<<<dim3(NBATCH / 128, NXD / 128), 256, 0, stream>>>(
      (const u16*)Zb, KFIN, (const u16*)Wfin, KFIN, out, NXD, KFIN);
}